// Round 16
// baseline (94.314 us; speedup 1.0000x reference)
//
#include <hip/hip_runtime.h>
#include <hip/hip_bf16.h>
#include <math.h>

#define DEV __device__ __forceinline__

typedef __attribute__((ext_vector_type(4))) float f32x4;
typedef __attribute__((ext_vector_type(8))) short bf16x8;

DEV unsigned short f2bf(float v) {
    __hip_bfloat16 h = __float2bfloat16(v);
    return *reinterpret_cast<unsigned short*>(&h);
}
DEV unsigned pk2(float a, float b) {          // RNE pack 2xf32 -> 2xbf16 (v_cvt_pk), a=low
    union { __hip_bfloat162 b2; unsigned u; } cv;
    cv.b2 = __float22bfloat162_rn(float2{a, b});
    return cv.u;
}

// ============================ quantum gates (compile-time unrolled) ============================
template<int B>
DEV void ry_b(float* sr, float* si, float c, float s) {
    #pragma unroll
    for (int i = 0; i < 16; ++i) if (!(i & B)) {
        int j = i | B;
        float r0 = sr[i], m0 = si[i], r1 = sr[j], m1 = si[j];
        sr[i] = c * r0 - s * r1;  si[i] = c * m0 - s * m1;
        sr[j] = s * r0 + c * r1;  si[j] = s * m0 + c * m1;
    }
}
template<int B>
DEV void rz_b(float* sr, float* si, float c, float s) {
    #pragma unroll
    for (int i = 0; i < 16; ++i) {
        float xr = sr[i], xi = si[i];
        if (!(i & B)) { sr[i] = c * xr + s * xi;  si[i] = c * xi - s * xr; }
        else          { sr[i] = c * xr - s * xi;  si[i] = c * xi + s * xr; }
    }
}
template<int BC, int BT>
DEV void cnot_b(float* sr, float* si) {
    #pragma unroll
    for (int i = 0; i < 16; ++i) if ((i & BC) && !(i & BT)) {
        int j = i | BT;
        float tr = sr[i]; sr[i] = sr[j]; sr[j] = tr;
        float ti = si[i]; si[i] = si[j]; si[j] = ti;
    }
}
template<int A, int Bw>
DEV void ansatz(float* sr, float* si, const float* cc, const float* ss) {
    constexpr int BA = 8 >> A, BB = 8 >> Bw;
    ry_b<BA>(sr, si, cc[0], ss[0]);
    rz_b<BA>(sr, si, cc[1], ss[1]);
    ry_b<BB>(sr, si, cc[2], ss[2]);
    rz_b<BB>(sr, si, cc[3], ss[3]);
    cnot_b<BA, BB>(sr, si);
    ry_b<BA>(sr, si, cc[4], ss[4]);
    rz_b<BA>(sr, si, cc[5], ss[5]);
    ry_b<BB>(sr, si, cc[6], ss[6]);
}

// ============================ prep: weight transposes + ansatz-unitary fold ============================
__global__ void prep_kernel(const float* __restrict__ w1,   // (64,1,3,3)
                            const float* __restrict__ w2,   // (16,64,3,3)
                            const float* __restrict__ w3,   // (4,16,3,3)
                            const float* __restrict__ qp,   // (2,7)
                            const float* __restrict__ fc1w, // (64,196)
                            const float* __restrict__ fc2w, // (128,64)
                            const float* __restrict__ fc3w, // (64,128)
                            const float* __restrict__ fc4w, // (10,64)
                            unsigned short* __restrict__ w1b, // 2048 bf16
                            unsigned short* __restrict__ w2b, // 9216 bf16
                            float* __restrict__ w3c,         // 576: [c][tap][ic]
                            float* __restrict__ ab,          // 512
                            float* __restrict__ fc1t,        // (196,64)
                            float* __restrict__ fc2t,        // (64,128)
                            float* __restrict__ fc3t,        // (128,64)
                            float* __restrict__ fc4t)        // (64,10)
{
    int t = blockIdx.x * blockDim.x + threadIdx.x;
    int NT = gridDim.x * blockDim.x;
    for (int i = t; i < 2048; i += NT) {
        int j = i & 7, oc = (i >> 3) & 63, fqq = i >> 9;
        int tap = fqq * 8 + j;
        w1b[i] = tap < 9 ? f2bf(w1[oc * 9 + tap]) : (unsigned short)0;
    }
    for (int i = t; i < 9216; i += NT) {
        int j = i & 7, oc = (i >> 3) & 15, fq = (i >> 7) & 3, f = i >> 9;
        int tap = f >> 1, kk = f & 1;
        int s = kk * 32 + fq * 8 + j;            // K slot
        int ic = (s & 3) * 16 + (s >> 2);        // channel-slot permutation
        w2b[i] = f2bf(w2[(oc * 64 + ic) * 9 + tap]);
    }
    for (int i = t; i < 576; i += NT) {
        int ic = i & 15, tap = (i >> 4) % 9, c = i / 144;
        w3c[i] = w3[(c * 16 + ic) * 9 + tap];
    }
    for (int i = t; i < 12544; i += NT) { int j = i / 196, k = i % 196; fc1t[k * 64 + j] = fc1w[i]; }
    for (int i = t; i < 8192;  i += NT) { int j = i / 64,  k = i % 64;  fc2t[k * 128 + j] = fc2w[i]; }
    for (int i = t; i < 8192;  i += NT) { int j = i / 128, k = i % 128; fc3t[k * 64 + j] = fc3w[i]; }
    for (int i = t; i < 640;   i += NT) { int j = i / 64,  k = i % 64;  fc4t[k * 10 + j] = fc4w[i]; }

    // fold the qp-only ansatz chain into U (16x16 complex); thread b = basis column b
    if (blockIdx.x == 0 && threadIdx.x < 16) {
        int b = threadIdx.x;
        float cs0[7], sn0[7], cs1[7], sn1[7];
        #pragma unroll
        for (int k = 0; k < 7; ++k) {
            __sincosf(qp[k] * 0.5f, &sn0[k], &cs0[k]);
            __sincosf(qp[7 + k] * 0.5f, &sn1[k], &cs1[k]);
        }
        float sr[16], si[16];
        #pragma unroll
        for (int i = 0; i < 16; ++i) { sr[i] = (i == b) ? 1.f : 0.f; si[i] = 0.f; }
        ansatz<0, 1>(sr, si, cs0, sn0);
        ansatz<1, 2>(sr, si, cs0, sn0);
        ansatz<2, 3>(sr, si, cs0, sn0);
        ansatz<3, 0>(sr, si, cs0, sn0);
        ansatz<0, 1>(sr, si, cs1, sn1);
        ansatz<1, 2>(sr, si, cs1, sn1);
        ansatz<2, 3>(sr, si, cs1, sn1);
        ansatz<3, 0>(sr, si, cs1, sn1);
        #pragma unroll
        for (int i = 0; i < 16; ++i) {
            ab[(i * 16 + b) * 2]     = sr[i];
            ab[(i * 16 + b) * 2 + 1] = si[i];
        }
    }
}

// ============================ fused conv1+pool+conv2+pool (both MFMA) ============================
// r13 structure (measured best): ring-zeroed pin/in_b/out2, 2 barriers total.
__global__ __launch_bounds__(256, 4) void conv12_kernel(
    const float* __restrict__ x,
    const float* __restrict__ b1, const unsigned short* __restrict__ w1b,
    const unsigned short* __restrict__ w2b,
    const float* __restrict__ b2, float* __restrict__ out2)
{
    __shared__ __align__(128) char lds_all[36864];
    float* pin = (float*)lds_all;                         // [30][34] f32, ring-zeroed
    char* in_b = lds_all + 4096;                          // 32 KB swizzled [256 grid][64 slots] bf16
    int t = threadIdx.x, lane = t & 63, wv = t >> 6;
    int fq = lane >> 4, fr = lane & 15;
    int n = blockIdx.x;

    // conv2 B fragments (L2-resident)
    bf16x8 bfrag[18];
    const bf16x8* wb = (const bf16x8*)w2b;
    #pragma unroll
    for (int f = 0; f < 18; ++f) bfrag[f] = wb[(f * 4 + fq) * 16 + fr];
    // conv1 B fragments + biases
    bf16x8 w1f[4];
    const bf16x8* wb1 = (const bf16x8*)w1b;
    float b1v[4];
    #pragma unroll
    for (int nt = 0; nt < 4; ++nt) {
        w1f[nt] = wb1[fq * 64 + nt * 16 + fr];
        b1v[nt] = b1[nt * 16 + fr];
    }
    float b2v = b2[fr];

    // zero the 60 pad cells of the swizzled tile (128 B each)
    for (int i = t; i < 480; i += 256) {
        int ci = i >> 3, sub = i & 7;
        int g;
        if (ci < 16)      g = ci;                  // row 0
        else if (ci < 32) g = 240 + (ci - 16);     // row 15
        else if (ci < 46) g = (ci - 31) * 16;      // col 0, rows 1..14
        else              g = (ci - 45) * 16 + 15; // col 15, rows 1..14
        *(f32x4*)(in_b + g * 128 + sub * 16) = f32x4{0.f, 0.f, 0.f, 0.f};
    }
    // zero ONLY pin's pad ring (rows 0/29, cols 0/29) — disjoint from staged interior
    if (t < 124) {
        int row, col;
        if (t < 68) { row = (t < 34) ? 0 : 29; col = (t < 34) ? t : t - 34; }
        else {
            int j = t - 68;
            if (j < 28) { row = j + 1;  col = 0; }
            else        { row = j - 27; col = 29; }
        }
        pin[row * 34 + col] = 0.f;
    }
    // zero out2's pad ring (32 cells x 16 ch = 128 float4) — global, no LDS dependency
    if (t >= 124 && t < 252) {
        int tt = t - 124;
        int cell = tt >> 2, comp = tt & 3;
        int pos;
        if (cell < 9)       pos = cell;                    // row 0
        else if (cell < 18) pos = 72 + (cell - 9);         // row 8
        else if (cell < 25) pos = (cell - 17) * 9;         // col 0, rows 1..7
        else                pos = (cell - 24) * 9 + 8;     // col 8, rows 1..7
        *reinterpret_cast<float4*>(out2 + (size_t)n * 1296 + pos * 16 + comp * 4)
            = float4{0.f, 0.f, 0.f, 0.f};
    }
    // stage image interior (disjoint from ring zeroing -> no barrier needed before)
    for (int i = t; i < 784; i += 256) pin[(i / 28 + 1) * 34 + (i % 28) + 1] = x[n * 784 + i];
    __syncthreads();

    // ---------------- phase 1: conv1 via MFMA + in-lane pool ----------------
    for (int tile = wv; tile < 49; tile += 4) {
        int pooledA = tile * 4 + (fr >> 2);
        int pyA = pooledA / 14, pxA = pooledA - pyA * 14;
        int Y = 2 * pyA + ((fr >> 1) & 1), X = 2 * pxA + (fr & 1);
        const float* ap = pin + Y * 34 + X + (fq == 1 ? 70 : 0);  // fq=1: j0 = tap8 @(+2,+2)
        float q0 = ap[0],  q1 = ap[1],  q2 = ap[2];
        float q3 = ap[34], q4 = ap[35], q5 = ap[36];
        float q6 = ap[68], q7 = ap[69];
        union { uint4 u; bf16x8 v; } A;
        A.u.x = pk2(q0, q1); A.u.y = pk2(q2, q3);
        A.u.z = pk2(q4, q5); A.u.w = pk2(q6, q7);

        f32x4 a0 = {0.f,0.f,0.f,0.f}, a1 = {0.f,0.f,0.f,0.f},
              a2 = {0.f,0.f,0.f,0.f}, a3 = {0.f,0.f,0.f,0.f};
        a0 = __builtin_amdgcn_mfma_f32_16x16x32_bf16(A.v, w1f[0], a0, 0, 0, 0);
        a1 = __builtin_amdgcn_mfma_f32_16x16x32_bf16(A.v, w1f[1], a1, 0, 0, 0);
        a2 = __builtin_amdgcn_mfma_f32_16x16x32_bf16(A.v, w1f[2], a2, 0, 0, 0);
        a3 = __builtin_amdgcn_mfma_f32_16x16x32_bf16(A.v, w1f[3], a3, 0, 0, 0);

        int pooled = tile * 4 + fq;          // 0..195
        int py = pooled / 14, px = pooled - py * 14;
        int grid = (py + 1) * 16 + (px + 1);
        unsigned swz = (unsigned)(grid & 7) << 4;
        float v0 = fmaxf(fmaxf(fmaxf(a0[0], a0[1]), fmaxf(a0[2], a0[3])) + b1v[0], 0.f);
        float v1 = fmaxf(fmaxf(fmaxf(a1[0], a1[1]), fmaxf(a1[2], a1[3])) + b1v[1], 0.f);
        float v2 = fmaxf(fmaxf(fmaxf(a2[0], a2[1]), fmaxf(a2[2], a2[3])) + b1v[2], 0.f);
        float v3 = fmaxf(fmaxf(fmaxf(a3[0], a3[1]), fmaxf(a3[2], a3[3])) + b1v[3], 0.f);
        uint2 w; w.x = pk2(v0, v1); w.y = pk2(v2, v3);    // slots fr*4 .. fr*4+3
        *reinterpret_cast<uint2*>(in_b + (((unsigned)grid * 128 + (unsigned)fr * 8) ^ swz)) = w;
    }
    __syncthreads();

    // ---------------- phase 2: conv2 via MFMA, in-lane pool, direct store ----------------
    for (int tile = wv; tile < 13; tile += 4) {
        f32x4 acc = {0.f, 0.f, 0.f, 0.f};
        int pv = tile * 4 + (fr >> 2); pv = pv > 48 ? 48 : pv;   // clamp tail rows
        int sub = fr & 3;
        int y7 = pv / 7, x7 = pv - y7 * 7;
        int y = 2 * y7 + (sub >> 1), xx = 2 * x7 + (sub & 1);    // pre-pool pos 0..13
        int g0 = y * 16 + xx;
        int vb = g0 * 128 + fq * 16;
        #pragma unroll
        for (int ky = 0; ky < 3; ++ky)
            #pragma unroll
            for (int kx = 0; kx < 3; ++kx) {
                int dg = ky * 16 + kx;
                int msk = ((g0 + dg) & 7) << 4;
                int lin = vb + dg * 128;
                bf16x8 a0 = *(const bf16x8*)(in_b + (lin ^ msk));
                acc = __builtin_amdgcn_mfma_f32_16x16x32_bf16(a0, bfrag[(ky * 3 + kx) * 2], acc, 0, 0, 0);
                bf16x8 a1 = *(const bf16x8*)(in_b + ((lin | 64) ^ msk));
                acc = __builtin_amdgcn_mfma_f32_16x16x32_bf16(a1, bfrag[(ky * 3 + kx) * 2 + 1], acc, 0, 0, 0);
            }
        int pooled2 = tile * 4 + fq;                 // 0..51
        if (pooled2 < 49) {
            float m = fmaxf(fmaxf(acc[0], acc[1]), fmaxf(acc[2], acc[3]));
            int y9 = pooled2 / 7, x9 = pooled2 - y9 * 7;
            out2[(size_t)n * 1296 + ((y9 + 1) * 9 + (x9 + 1)) * 16 + fr] =
                fmaxf(m + b2v, 0.f);
        }
    }
}

// ============================ fused conv3+quantum+MLP (1 image/block, 4 waves) ============================
// out2 padded NHWC (2048, 9x9, 16), ab = U(16x16 complex) -> out:(2048,10)
// Stage A: thread=(patch,ch) conv3+sincos; Stage B: thread=(patch,quarter) 4 U-rows;
// Stage C: reduce -> qr; fc: K-split across 4 waves + LDS reduce. 2048 blocks -> high occupancy.
__global__ __launch_bounds__(256, 4) void qfc_kernel(
    const float* __restrict__ out2, const float* __restrict__ w3c,
    const float* __restrict__ b3, const float* __restrict__ ab,
    const float* __restrict__ fc1t, const float* __restrict__ fb1,
    const float* __restrict__ fc2t, const float* __restrict__ fb2,
    const float* __restrict__ fc3t, const float* __restrict__ fb3,
    const float* __restrict__ fc4t, const float* __restrict__ fb4,
    float* __restrict__ out)
{
    __shared__ float2 cwsw[196];                 // (patch, ch) -> {cos, sin}
    __shared__ float4 part[196];                 // (patch, quarter) -> partial e0..e3
    __shared__ __align__(16) float qr[196];
    __shared__ float red[4][128];
    __shared__ float h1[64], h2[128], h3[64];
    int t = threadIdx.x, wv = t >> 6, lane = t & 63;
    int n = blockIdx.x;
    const float* in = out2 + (size_t)n * 1296;

    // ---- stage A: conv3 channel + leaky + sigmoid + sincos ----
    if (t < 196) {
        int p = t >> 2, c = t & 3;
        int py = p / 7, px = p - py * 7;
        float acc = b3[c];
        #pragma unroll
        for (int ky = 0; ky < 3; ++ky)
            #pragma unroll
            for (int kx = 0; kx < 3; ++kx) {
                const float* cp = in + ((py + ky) * 9 + (px + kx)) * 16;  // pad ring is zero
                const float* wp = w3c + (c * 9 + ky * 3 + kx) * 16;
                #pragma unroll
                for (int icq = 0; icq < 4; ++icq) {
                    float4 dv  = *reinterpret_cast<const float4*>(cp + icq * 4);
                    float4 wv4 = *reinterpret_cast<const float4*>(wp + icq * 4);
                    acc = fmaf(wv4.x, dv.x, acc);
                    acc = fmaf(wv4.y, dv.y, acc);
                    acc = fmaf(wv4.z, dv.z, acc);
                    acc = fmaf(wv4.w, dv.w, acc);
                }
            }
        float z = acc > 0.f ? acc : 0.01f * acc;
        float sg = 1.f / (1.f + __expf(-z));
        float sv, cv;
        __sincosf(1.5707963267948966f * sg, &sv, &cv);
        cwsw[t] = float2{cv, sv};
    }
    __syncthreads();

    // ---- stage B: product state + 4 U-rows per thread ----
    if (t < 196) {
        int p = t >> 2, qd = t & 3;
        float2 c0 = cwsw[p * 4 + 0];
        float2 c1 = cwsw[p * 4 + 1];
        float2 c2 = cwsw[p * 4 + 2];
        float2 c3 = cwsw[p * 4 + 3];
        float p01[4] = { c0.x*c1.x, c0.x*c1.y, c0.y*c1.x, c0.y*c1.y };
        float p23[4] = { c2.x*c3.x, c2.x*c3.y, c2.y*c3.x, c2.y*c3.y };
        float v[16];
        #pragma unroll
        for (int i = 0; i < 16; ++i) v[i] = p01[i >> 2] * p23[i & 3];

        float e0 = 0.f, e1 = 0.f, e2 = 0.f, e3 = 0.f;
        #pragma unroll
        for (int ii = 0; ii < 4; ++ii) {
            int i = qd * 4 + ii;
            const float* row = ab + i * 32;
            float re = 0.f, im = 0.f;
            #pragma unroll
            for (int k = 0; k < 16; ++k) {
                re = fmaf(row[k * 2],     v[k], re);
                im = fmaf(row[k * 2 + 1], v[k], im);
            }
            float p2 = re * re + im * im;
            e0 += (i & 8) ? -p2 : p2;
            e1 += (i & 4) ? -p2 : p2;
            e2 += (i & 2) ? -p2 : p2;
            e3 += (i & 1) ? -p2 : p2;
        }
        part[t] = float4{e0, e1, e2, e3};
    }
    __syncthreads();

    // ---- stage C: reduce quarters -> qr ----
    if (t < 49) {
        float4 s0 = part[t * 4 + 0], s1 = part[t * 4 + 1];
        float4 s2 = part[t * 4 + 2], s3 = part[t * 4 + 3];
        float4 r;
        r.x = (s0.x + s1.x) + (s2.x + s3.x);
        r.y = (s0.y + s1.y) + (s2.y + s3.y);
        r.z = (s0.z + s1.z) + (s2.z + s3.z);
        r.w = (s0.w + s1.w) + (s2.w + s3.w);
        *reinterpret_cast<float4*>(&qr[t * 4]) = r;
    }
    __syncthreads();

    // ---- fc1: K=196 split 49/wave ----
    {
        float s = 0.f;
        int k0 = 49 * wv;
        for (int k = 0; k < 49; ++k)
            s = fmaf(fc1t[(k0 + k) * 64 + lane], qr[k0 + k], s);
        red[wv][lane] = s;
    }
    __syncthreads();
    if (wv == 0)
        h1[lane] = fmaxf(fb1[lane] + ((red[0][lane] + red[1][lane]) + (red[2][lane] + red[3][lane])), 0.f);
    __syncthreads();

    // ---- fc2: K=64 split 16/wave, 128 outputs ----
    {
        float s0 = 0.f, s1 = 0.f;
        int k0 = 16 * wv;
        for (int k = 0; k < 16; ++k) {
            float v = h1[k0 + k];
            s0 = fmaf(fc2t[(k0 + k) * 128 + lane],      v, s0);
            s1 = fmaf(fc2t[(k0 + k) * 128 + lane + 64], v, s1);
        }
        red[wv][lane]      = s0;
        red[wv][lane + 64] = s1;
    }
    __syncthreads();
    if (wv == 0) {
        h2[lane]      = fb2[lane]      + ((red[0][lane] + red[1][lane]) + (red[2][lane] + red[3][lane]));
        h2[lane + 64] = fb2[lane + 64] + ((red[0][lane + 64] + red[1][lane + 64]) + (red[2][lane + 64] + red[3][lane + 64]));
    }
    __syncthreads();

    // ---- fc3: K=128 split 32/wave ----
    {
        float s = 0.f;
        int k0 = 32 * wv;
        for (int k = 0; k < 32; ++k)
            s = fmaf(fc3t[(k0 + k) * 64 + lane], h2[k0 + k], s);
        red[wv][lane] = s;
    }
    __syncthreads();
    if (wv == 0)
        h3[lane] = fmaxf(fb3[lane] + ((red[0][lane] + red[1][lane]) + (red[2][lane] + red[3][lane])), 0.f);
    __syncthreads();

    // ---- fc4: K=64 split 16/wave, 10 outputs ----
    if (lane < 10) {
        float s = 0.f;
        int k0 = 16 * wv;
        for (int k = 0; k < 16; ++k)
            s = fmaf(fc4t[(k0 + k) * 10 + lane], h3[k0 + k], s);
        red[wv][lane] = s;
    }
    __syncthreads();
    if (t < 10)
        out[(size_t)n * 10 + t] = fb4[t] + ((red[0][t] + red[1][t]) + (red[2][t] + red[3][t]));
}

// ============================ launch ============================
extern "C" void kernel_launch(void* const* d_in, const int* in_sizes, int n_in,
                              void* d_out, int out_size, void* d_ws, size_t ws_size,
                              hipStream_t stream) {
    const float* x      = (const float*)d_in[0];
    const float* c1w    = (const float*)d_in[1];
    const float* c1b    = (const float*)d_in[2];
    const float* c2w    = (const float*)d_in[3];
    const float* c2b    = (const float*)d_in[4];
    const float* c3w    = (const float*)d_in[5];
    const float* c3b    = (const float*)d_in[6];
    const float* qp     = (const float*)d_in[7];
    const float* fc1w   = (const float*)d_in[8];
    const float* fc1b   = (const float*)d_in[9];
    const float* fc2w   = (const float*)d_in[10];
    const float* fc2b   = (const float*)d_in[11];
    const float* fc3w   = (const float*)d_in[12];
    const float* fc3b   = (const float*)d_in[13];
    const float* fc4w   = (const float*)d_in[14];
    const float* fc4b   = (const float*)d_in[15];
    float* out = (float*)d_out;

    float* ws = (float*)d_ws;
    unsigned short* w2b = (unsigned short*)ws;            // 9216 bf16 (4608 float slots)
    unsigned short* w1b = (unsigned short*)(ws + 4608);   // 2048 bf16 (1024 float slots)
    float* w3c  = ws + 5632;                              // 576
    float* abm  = ws + 6208;                              // 512
    float* fc1t = ws + 6720;                              // 12544
    float* fc2t = fc1t + 12544;                           // 8192
    float* fc3t = fc2t + 8192;                            // 8192
    float* fc4t = fc3t + 8192;                            // 640
    float* out2 = fc4t + 640;                             // 2048*1296 f32 (padded 9x9x16)

    prep_kernel<<<40, 256, 0, stream>>>(c1w, c2w, c3w, qp, fc1w, fc2w, fc3w, fc4w,
                                        w1b, w2b, w3c, abm, fc1t, fc2t, fc3t, fc4t);
    conv12_kernel<<<2048, 256, 0, stream>>>(x, c1b, w1b, w2b, c2b, out2);
    qfc_kernel<<<2048, 256, 0, stream>>>(out2, w3c, c3b, abm,
                                         fc1t, fc1b, fc2t, fc2b,
                                         fc3t, fc3b, fc4t, fc4b, out);
}

// Round 17
// 68.686 us; speedup vs baseline: 1.3731x; 1.3731x over previous
//
#include <hip/hip_runtime.h>
#include <hip/hip_bf16.h>
#include <math.h>

#define DEV __device__ __forceinline__

typedef __attribute__((ext_vector_type(4))) float f32x4;
typedef __attribute__((ext_vector_type(8))) short bf16x8;

DEV unsigned short f2bf(float v) {
    __hip_bfloat16 h = __float2bfloat16(v);
    return *reinterpret_cast<unsigned short*>(&h);
}
DEV unsigned pk2(float a, float b) {          // RNE pack 2xf32 -> 2xbf16 (v_cvt_pk), a=low
    union { __hip_bfloat162 b2; unsigned u; } cv;
    cv.b2 = __float22bfloat162_rn(float2{a, b});
    return cv.u;
}

// ============================ quantum gates (compile-time unrolled) ============================
template<int B>
DEV void ry_b(float* sr, float* si, float c, float s) {
    #pragma unroll
    for (int i = 0; i < 16; ++i) if (!(i & B)) {
        int j = i | B;
        float r0 = sr[i], m0 = si[i], r1 = sr[j], m1 = si[j];
        sr[i] = c * r0 - s * r1;  si[i] = c * m0 - s * m1;
        sr[j] = s * r0 + c * r1;  si[j] = s * m0 + c * m1;
    }
}
template<int B>
DEV void rz_b(float* sr, float* si, float c, float s) {
    #pragma unroll
    for (int i = 0; i < 16; ++i) {
        float xr = sr[i], xi = si[i];
        if (!(i & B)) { sr[i] = c * xr + s * xi;  si[i] = c * xi - s * xr; }
        else          { sr[i] = c * xr - s * xi;  si[i] = c * xi + s * xr; }
    }
}
template<int BC, int BT>
DEV void cnot_b(float* sr, float* si) {
    #pragma unroll
    for (int i = 0; i < 16; ++i) if ((i & BC) && !(i & BT)) {
        int j = i | BT;
        float tr = sr[i]; sr[i] = sr[j]; sr[j] = tr;
        float ti = si[i]; si[i] = si[j]; si[j] = ti;
    }
}
template<int A, int Bw>
DEV void ansatz(float* sr, float* si, const float* cc, const float* ss) {
    constexpr int BA = 8 >> A, BB = 8 >> Bw;
    ry_b<BA>(sr, si, cc[0], ss[0]);
    rz_b<BA>(sr, si, cc[1], ss[1]);
    ry_b<BB>(sr, si, cc[2], ss[2]);
    rz_b<BB>(sr, si, cc[3], ss[3]);
    cnot_b<BA, BB>(sr, si);
    ry_b<BA>(sr, si, cc[4], ss[4]);
    rz_b<BA>(sr, si, cc[5], ss[5]);
    ry_b<BB>(sr, si, cc[6], ss[6]);
}

// ============================ prep: weight transposes + ansatz-unitary fold ============================
__global__ void prep_kernel(const float* __restrict__ w1,   // (64,1,3,3)
                            const float* __restrict__ w2,   // (16,64,3,3)
                            const float* __restrict__ w3,   // (4,16,3,3)
                            const float* __restrict__ qp,   // (2,7)
                            const float* __restrict__ fc1w, // (64,196)
                            const float* __restrict__ fc2w, // (128,64)
                            const float* __restrict__ fc3w, // (64,128)
                            const float* __restrict__ fc4w, // (10,64)
                            unsigned short* __restrict__ w1b, // 2048 bf16
                            unsigned short* __restrict__ w2b, // 9216 bf16
                            float* __restrict__ w3t,         // 576
                            float* __restrict__ ab,          // 512
                            float* __restrict__ fc1t,        // (196,64)
                            float* __restrict__ fc2t,        // (64,128)
                            float* __restrict__ fc3t,        // (128,64)
                            float* __restrict__ fc4t)        // (64,10)
{
    int t = blockIdx.x * blockDim.x + threadIdx.x;
    int NT = gridDim.x * blockDim.x;
    for (int i = t; i < 2048; i += NT) {
        int j = i & 7, oc = (i >> 3) & 63, fqq = i >> 9;
        int tap = fqq * 8 + j;
        w1b[i] = tap < 9 ? f2bf(w1[oc * 9 + tap]) : (unsigned short)0;
    }
    for (int i = t; i < 9216; i += NT) {
        int j = i & 7, oc = (i >> 3) & 15, fq = (i >> 7) & 3, f = i >> 9;
        int tap = f >> 1, kk = f & 1;
        int s = kk * 32 + fq * 8 + j;            // K slot
        int ic = (s & 3) * 16 + (s >> 2);        // channel-slot permutation
        w2b[i] = f2bf(w2[(oc * 64 + ic) * 9 + tap]);
    }
    for (int i = t; i < 576; i += NT) {
        int c = i & 3, ch = (i >> 2) & 15, tap = i >> 6;
        w3t[i] = w3[(c * 16 + ch) * 9 + tap];
    }
    for (int i = t; i < 12544; i += NT) { int j = i / 196, k = i % 196; fc1t[k * 64 + j] = fc1w[i]; }
    for (int i = t; i < 8192;  i += NT) { int j = i / 64,  k = i % 64;  fc2t[k * 128 + j] = fc2w[i]; }
    for (int i = t; i < 8192;  i += NT) { int j = i / 128, k = i % 128; fc3t[k * 64 + j] = fc3w[i]; }
    for (int i = t; i < 640;   i += NT) { int j = i / 64,  k = i % 64;  fc4t[k * 10 + j] = fc4w[i]; }

    // fold the qp-only ansatz chain into U (16x16 complex); thread b = basis column b
    if (blockIdx.x == 0 && threadIdx.x < 16) {
        int b = threadIdx.x;
        float cs0[7], sn0[7], cs1[7], sn1[7];
        #pragma unroll
        for (int k = 0; k < 7; ++k) {
            __sincosf(qp[k] * 0.5f, &sn0[k], &cs0[k]);
            __sincosf(qp[7 + k] * 0.5f, &sn1[k], &cs1[k]);
        }
        float sr[16], si[16];
        #pragma unroll
        for (int i = 0; i < 16; ++i) { sr[i] = (i == b) ? 1.f : 0.f; si[i] = 0.f; }
        ansatz<0, 1>(sr, si, cs0, sn0);
        ansatz<1, 2>(sr, si, cs0, sn0);
        ansatz<2, 3>(sr, si, cs0, sn0);
        ansatz<3, 0>(sr, si, cs0, sn0);
        ansatz<0, 1>(sr, si, cs1, sn1);
        ansatz<1, 2>(sr, si, cs1, sn1);
        ansatz<2, 3>(sr, si, cs1, sn1);
        ansatz<3, 0>(sr, si, cs1, sn1);
        #pragma unroll
        for (int i = 0; i < 16; ++i) {
            ab[(i * 16 + b) * 2]     = sr[i];
            ab[(i * 16 + b) * 2 + 1] = si[i];
        }
    }
}

// ============================ fused conv1+pool+conv2+pool (both MFMA) ============================
// r13 structure (measured best): ring-zeroed pin/in_b/out2, 2 barriers total.
__global__ __launch_bounds__(256, 4) void conv12_kernel(
    const float* __restrict__ x,
    const float* __restrict__ b1, const unsigned short* __restrict__ w1b,
    const unsigned short* __restrict__ w2b,
    const float* __restrict__ b2, float* __restrict__ out2)
{
    __shared__ __align__(128) char lds_all[36864];
    float* pin = (float*)lds_all;                         // [30][34] f32, ring-zeroed
    char* in_b = lds_all + 4096;                          // 32 KB swizzled [256 grid][64 slots] bf16
    int t = threadIdx.x, lane = t & 63, wv = t >> 6;
    int fq = lane >> 4, fr = lane & 15;
    int n = blockIdx.x;

    // conv2 B fragments (L2-resident)
    bf16x8 bfrag[18];
    const bf16x8* wb = (const bf16x8*)w2b;
    #pragma unroll
    for (int f = 0; f < 18; ++f) bfrag[f] = wb[(f * 4 + fq) * 16 + fr];
    // conv1 B fragments + biases
    bf16x8 w1f[4];
    const bf16x8* wb1 = (const bf16x8*)w1b;
    float b1v[4];
    #pragma unroll
    for (int nt = 0; nt < 4; ++nt) {
        w1f[nt] = wb1[fq * 64 + nt * 16 + fr];
        b1v[nt] = b1[nt * 16 + fr];
    }
    float b2v = b2[fr];

    // zero the 60 pad cells of the swizzled tile (128 B each)
    for (int i = t; i < 480; i += 256) {
        int ci = i >> 3, sub = i & 7;
        int g;
        if (ci < 16)      g = ci;                  // row 0
        else if (ci < 32) g = 240 + (ci - 16);     // row 15
        else if (ci < 46) g = (ci - 31) * 16;      // col 0, rows 1..14
        else              g = (ci - 45) * 16 + 15; // col 15, rows 1..14
        *(f32x4*)(in_b + g * 128 + sub * 16) = f32x4{0.f, 0.f, 0.f, 0.f};
    }
    // zero ONLY pin's pad ring (rows 0/29, cols 0/29) — disjoint from staged interior
    if (t < 124) {
        int row, col;
        if (t < 68) { row = (t < 34) ? 0 : 29; col = (t < 34) ? t : t - 34; }
        else {
            int j = t - 68;
            if (j < 28) { row = j + 1;  col = 0; }
            else        { row = j - 27; col = 29; }
        }
        pin[row * 34 + col] = 0.f;
    }
    // zero out2's pad ring (32 cells x 16 ch = 128 float4) — global, no LDS dependency
    if (t >= 124 && t < 252) {
        int tt = t - 124;
        int cell = tt >> 2, comp = tt & 3;
        int pos;
        if (cell < 9)       pos = cell;                    // row 0
        else if (cell < 18) pos = 72 + (cell - 9);         // row 8
        else if (cell < 25) pos = (cell - 17) * 9;         // col 0, rows 1..7
        else                pos = (cell - 24) * 9 + 8;     // col 8, rows 1..7
        *reinterpret_cast<float4*>(out2 + (size_t)n * 1296 + pos * 16 + comp * 4)
            = float4{0.f, 0.f, 0.f, 0.f};
    }
    // stage image interior (disjoint from ring zeroing -> no barrier needed before)
    for (int i = t; i < 784; i += 256) pin[(i / 28 + 1) * 34 + (i % 28) + 1] = x[n * 784 + i];
    __syncthreads();

    // ---------------- phase 1: conv1 via MFMA + in-lane pool ----------------
    for (int tile = wv; tile < 49; tile += 4) {
        int pooledA = tile * 4 + (fr >> 2);
        int pyA = pooledA / 14, pxA = pooledA - pyA * 14;
        int Y = 2 * pyA + ((fr >> 1) & 1), X = 2 * pxA + (fr & 1);
        const float* ap = pin + Y * 34 + X + (fq == 1 ? 70 : 0);  // fq=1: j0 = tap8 @(+2,+2)
        float q0 = ap[0],  q1 = ap[1],  q2 = ap[2];
        float q3 = ap[34], q4 = ap[35], q5 = ap[36];
        float q6 = ap[68], q7 = ap[69];
        union { uint4 u; bf16x8 v; } A;
        A.u.x = pk2(q0, q1); A.u.y = pk2(q2, q3);
        A.u.z = pk2(q4, q5); A.u.w = pk2(q6, q7);

        f32x4 a0 = {0.f,0.f,0.f,0.f}, a1 = {0.f,0.f,0.f,0.f},
              a2 = {0.f,0.f,0.f,0.f}, a3 = {0.f,0.f,0.f,0.f};
        a0 = __builtin_amdgcn_mfma_f32_16x16x32_bf16(A.v, w1f[0], a0, 0, 0, 0);
        a1 = __builtin_amdgcn_mfma_f32_16x16x32_bf16(A.v, w1f[1], a1, 0, 0, 0);
        a2 = __builtin_amdgcn_mfma_f32_16x16x32_bf16(A.v, w1f[2], a2, 0, 0, 0);
        a3 = __builtin_amdgcn_mfma_f32_16x16x32_bf16(A.v, w1f[3], a3, 0, 0, 0);

        int pooled = tile * 4 + fq;          // 0..195
        int py = pooled / 14, px = pooled - py * 14;
        int grid = (py + 1) * 16 + (px + 1);
        unsigned swz = (unsigned)(grid & 7) << 4;
        float v0 = fmaxf(fmaxf(fmaxf(a0[0], a0[1]), fmaxf(a0[2], a0[3])) + b1v[0], 0.f);
        float v1 = fmaxf(fmaxf(fmaxf(a1[0], a1[1]), fmaxf(a1[2], a1[3])) + b1v[1], 0.f);
        float v2 = fmaxf(fmaxf(fmaxf(a2[0], a2[1]), fmaxf(a2[2], a2[3])) + b1v[2], 0.f);
        float v3 = fmaxf(fmaxf(fmaxf(a3[0], a3[1]), fmaxf(a3[2], a3[3])) + b1v[3], 0.f);
        uint2 w; w.x = pk2(v0, v1); w.y = pk2(v2, v3);    // slots fr*4 .. fr*4+3
        *reinterpret_cast<uint2*>(in_b + (((unsigned)grid * 128 + (unsigned)fr * 8) ^ swz)) = w;
    }
    __syncthreads();

    // ---------------- phase 2: conv2 via MFMA, in-lane pool, direct store ----------------
    for (int tile = wv; tile < 13; tile += 4) {
        f32x4 acc = {0.f, 0.f, 0.f, 0.f};
        int pv = tile * 4 + (fr >> 2); pv = pv > 48 ? 48 : pv;   // clamp tail rows
        int sub = fr & 3;
        int y7 = pv / 7, x7 = pv - y7 * 7;
        int y = 2 * y7 + (sub >> 1), xx = 2 * x7 + (sub & 1);    // pre-pool pos 0..13
        int g0 = y * 16 + xx;
        int vb = g0 * 128 + fq * 16;
        #pragma unroll
        for (int ky = 0; ky < 3; ++ky)
            #pragma unroll
            for (int kx = 0; kx < 3; ++kx) {
                int dg = ky * 16 + kx;
                int msk = ((g0 + dg) & 7) << 4;
                int lin = vb + dg * 128;
                bf16x8 a0 = *(const bf16x8*)(in_b + (lin ^ msk));
                acc = __builtin_amdgcn_mfma_f32_16x16x32_bf16(a0, bfrag[(ky * 3 + kx) * 2], acc, 0, 0, 0);
                bf16x8 a1 = *(const bf16x8*)(in_b + ((lin | 64) ^ msk));
                acc = __builtin_amdgcn_mfma_f32_16x16x32_bf16(a1, bfrag[(ky * 3 + kx) * 2 + 1], acc, 0, 0, 0);
            }
        int pooled2 = tile * 4 + fq;                 // 0..51
        if (pooled2 < 49) {
            float m = fmaxf(fmaxf(acc[0], acc[1]), fmaxf(acc[2], acc[3]));
            int y9 = pooled2 / 7, x9 = pooled2 - y9 * 7;
            out2[(size_t)n * 1296 + ((y9 + 1) * 9 + (x9 + 1)) * 16 + fr] =
                fmaxf(m + b2v, 0.f);
        }
    }
}

// ============================ fused conv3+quantum+MLP (4 images/block, wave = image) ============================
// r13 structure (wave=image, shared weight stream -> L1 reuse), 4 img/block x 1024 blocks
// -> 4 blocks/CU resident (16 waves/CU) instead of r13's 1 block/CU.
__global__ __launch_bounds__(256) void qfc_kernel(
    const float* __restrict__ out2, const float* __restrict__ w3t,
    const float* __restrict__ b3, const float* __restrict__ ab,
    const float* __restrict__ fc1t, const float* __restrict__ fb1,
    const float* __restrict__ fc2t, const float* __restrict__ fb2,
    const float* __restrict__ fc3t, const float* __restrict__ fb3,
    const float* __restrict__ fc4t, const float* __restrict__ fb4,
    float* __restrict__ out)
{
    __shared__ float qr[4][196];
    __shared__ float h1[4][64], h2[4][128], h3[4][64];
    int t = threadIdx.x;
    int nb = blockIdx.x * 4;              // 1024 blocks x 4 = 2048

    // ---- patch phase: threads 0..195, one (image, patch) each ----
    if (t < 196) {
        int nl = t / 49, p = t - nl * 49;
        int n = nb + nl;
        int py = p / 7, px = p - py * 7;
        const float* in = out2 + (size_t)n * 1296;

        float acc0 = b3[0], acc1 = b3[1], acc2 = b3[2], acc3 = b3[3];
        #pragma unroll
        for (int ky = 0; ky < 3; ++ky)
            #pragma unroll
            for (int kx = 0; kx < 3; ++kx) {
                const float* cp = in + ((py + ky) * 9 + (px + kx)) * 16;   // pad ring is zero
                const float* wt = w3t + (ky * 3 + kx) * 64;                // uniform -> s_load
                #pragma unroll
                for (int icq = 0; icq < 4; ++icq) {
                    float4 v4 = *reinterpret_cast<const float4*>(cp + icq * 4);
                    const float* wq = wt + icq * 16;
                    acc0 = fmaf(wq[0],  v4.x, acc0); acc1 = fmaf(wq[1],  v4.x, acc1);
                    acc2 = fmaf(wq[2],  v4.x, acc2); acc3 = fmaf(wq[3],  v4.x, acc3);
                    acc0 = fmaf(wq[4],  v4.y, acc0); acc1 = fmaf(wq[5],  v4.y, acc1);
                    acc2 = fmaf(wq[6],  v4.y, acc2); acc3 = fmaf(wq[7],  v4.y, acc3);
                    acc0 = fmaf(wq[8],  v4.z, acc0); acc1 = fmaf(wq[9],  v4.z, acc1);
                    acc2 = fmaf(wq[10], v4.z, acc2); acc3 = fmaf(wq[11], v4.z, acc3);
                    acc0 = fmaf(wq[12], v4.w, acc0); acc1 = fmaf(wq[13], v4.w, acc1);
                    acc2 = fmaf(wq[14], v4.w, acc2); acc3 = fmaf(wq[15], v4.w, acc3);
                }
            }

        float cw[4], sw[4];
        {
            float az[4] = {acc0, acc1, acc2, acc3};
            #pragma unroll
            for (int c = 0; c < 4; ++c) {
                float z = az[c];
                z = z > 0.f ? z : 0.01f * z;
                float sg = 1.f / (1.f + __expf(-z));
                __sincosf(1.5707963267948966f * sg, &sw[c], &cw[c]);
            }
        }
        float p01[4] = { cw[0]*cw[1], cw[0]*sw[1], sw[0]*cw[1], sw[0]*sw[1] };
        float p23[4] = { cw[2]*cw[3], cw[2]*sw[3], sw[2]*cw[3], sw[2]*sw[3] };
        float v[16];
        #pragma unroll
        for (int i = 0; i < 16; ++i) v[i] = p01[i >> 2] * p23[i & 3];

        float e0 = 0.f, e1 = 0.f, e2 = 0.f, e3 = 0.f;
        #pragma unroll
        for (int i = 0; i < 16; ++i) {
            const float* row = ab + i * 32;          // uniform -> s_load
            float re = 0.f, im = 0.f;
            #pragma unroll
            for (int k = 0; k < 16; ++k) {
                re = fmaf(row[k * 2],     v[k], re);
                im = fmaf(row[k * 2 + 1], v[k], im);
            }
            float p2 = re * re + im * im;
            e0 += (i & 8) ? -p2 : p2;
            e1 += (i & 4) ? -p2 : p2;
            e2 += (i & 2) ? -p2 : p2;
            e3 += (i & 1) ? -p2 : p2;
        }
        *reinterpret_cast<float4*>(&qr[nl][p * 4]) = float4{e0, e1, e2, e3};
    }
    __syncthreads();

    // ---- fc phase: wave = image (all 4 waves stream the SAME weights -> L1 reuse) ----
    int wv = t >> 6, lane = t & 63;
    int n = nb + wv;
    float a = fb1[lane];
    for (int k = 0; k < 196; ++k) a = fmaf(fc1t[k * 64 + lane], qr[wv][k], a);
    h1[wv][lane] = fmaxf(a, 0.f);
    __syncthreads();
    float a0 = fb2[lane], a1 = fb2[lane + 64];
    for (int k = 0; k < 64; ++k) {
        float vv = h1[wv][k];
        a0 = fmaf(fc2t[k * 128 + lane], vv, a0);
        a1 = fmaf(fc2t[k * 128 + lane + 64], vv, a1);
    }
    h2[wv][lane] = a0; h2[wv][lane + 64] = a1;
    __syncthreads();
    a = fb3[lane];
    for (int k = 0; k < 128; ++k) a = fmaf(fc3t[k * 64 + lane], h2[wv][k], a);
    h3[wv][lane] = fmaxf(a, 0.f);
    __syncthreads();
    if (lane < 10) {
        a = fb4[lane];
        for (int k = 0; k < 64; ++k) a = fmaf(fc4t[k * 10 + lane], h3[wv][k], a);
        out[(size_t)n * 10 + lane] = a;
    }
}

// ============================ launch ============================
extern "C" void kernel_launch(void* const* d_in, const int* in_sizes, int n_in,
                              void* d_out, int out_size, void* d_ws, size_t ws_size,
                              hipStream_t stream) {
    const float* x      = (const float*)d_in[0];
    const float* c1w    = (const float*)d_in[1];
    const float* c1b    = (const float*)d_in[2];
    const float* c2w    = (const float*)d_in[3];
    const float* c2b    = (const float*)d_in[4];
    const float* c3w    = (const float*)d_in[5];
    const float* c3b    = (const float*)d_in[6];
    const float* qp     = (const float*)d_in[7];
    const float* fc1w   = (const float*)d_in[8];
    const float* fc1b   = (const float*)d_in[9];
    const float* fc2w   = (const float*)d_in[10];
    const float* fc2b   = (const float*)d_in[11];
    const float* fc3w   = (const float*)d_in[12];
    const float* fc3b   = (const float*)d_in[13];
    const float* fc4w   = (const float*)d_in[14];
    const float* fc4b   = (const float*)d_in[15];
    float* out = (float*)d_out;

    float* ws = (float*)d_ws;
    unsigned short* w2b = (unsigned short*)ws;            // 9216 bf16 (4608 float slots)
    unsigned short* w1b = (unsigned short*)(ws + 4608);   // 2048 bf16 (1024 float slots)
    float* w3t  = ws + 5632;                              // 576
    float* abm  = ws + 6208;                              // 512
    float* fc1t = ws + 6720;                              // 12544
    float* fc2t = fc1t + 12544;                           // 8192
    float* fc3t = fc2t + 8192;                            // 8192
    float* fc4t = fc3t + 8192;                            // 640
    float* out2 = fc4t + 640;                             // 2048*1296 f32 (padded 9x9x16)

    prep_kernel<<<40, 256, 0, stream>>>(c1w, c2w, c3w, qp, fc1w, fc2w, fc3w, fc4w,
                                        w1b, w2b, w3t, abm, fc1t, fc2t, fc3t, fc4t);
    conv12_kernel<<<2048, 256, 0, stream>>>(x, c1b, w1b, w2b, c2b, out2);
    qfc_kernel<<<1024, 256, 0, stream>>>(out2, w3t, c3b, abm,
                                         fc1t, fc1b, fc2t, fc2b,
                                         fc3t, fc3b, fc4t, fc4b, out);
}

// Round 19
// 63.367 us; speedup vs baseline: 1.4884x; 1.0839x over previous
//
#include <hip/hip_runtime.h>
#include <hip/hip_bf16.h>
#include <math.h>

#define DEV __device__ __forceinline__

typedef __attribute__((ext_vector_type(4))) float f32x4;
typedef __attribute__((ext_vector_type(8))) short bf16x8;

DEV unsigned short f2bf(float v) {
    __hip_bfloat16 h = __float2bfloat16(v);
    return *reinterpret_cast<unsigned short*>(&h);
}
DEV unsigned pk2(float a, float b) {          // RNE pack 2xf32 -> 2xbf16 (v_cvt_pk), a=low
    union { __hip_bfloat162 b2; unsigned u; } cv;
    cv.b2 = __float22bfloat162_rn(float2{a, b});
    return cv.u;
}

// ============================ quantum gates (compile-time unrolled) ============================
template<int B>
DEV void ry_b(float* sr, float* si, float c, float s) {
    #pragma unroll
    for (int i = 0; i < 16; ++i) if (!(i & B)) {
        int j = i | B;
        float r0 = sr[i], m0 = si[i], r1 = sr[j], m1 = si[j];
        sr[i] = c * r0 - s * r1;  si[i] = c * m0 - s * m1;
        sr[j] = s * r0 + c * r1;  si[j] = s * m0 + c * m1;
    }
}
template<int B>
DEV void rz_b(float* sr, float* si, float c, float s) {
    #pragma unroll
    for (int i = 0; i < 16; ++i) {
        float xr = sr[i], xi = si[i];
        if (!(i & B)) { sr[i] = c * xr + s * xi;  si[i] = c * xi - s * xr; }
        else          { sr[i] = c * xr - s * xi;  si[i] = c * xi + s * xr; }
    }
}
template<int BC, int BT>
DEV void cnot_b(float* sr, float* si) {
    #pragma unroll
    for (int i = 0; i < 16; ++i) if ((i & BC) && !(i & BT)) {
        int j = i | BT;
        float tr = sr[i]; sr[i] = sr[j]; sr[j] = tr;
        float ti = si[i]; si[i] = si[j]; si[j] = ti;
    }
}
template<int A, int Bw>
DEV void ansatz(float* sr, float* si, const float* cc, const float* ss) {
    constexpr int BA = 8 >> A, BB = 8 >> Bw;
    ry_b<BA>(sr, si, cc[0], ss[0]);
    rz_b<BA>(sr, si, cc[1], ss[1]);
    ry_b<BB>(sr, si, cc[2], ss[2]);
    rz_b<BB>(sr, si, cc[3], ss[3]);
    cnot_b<BA, BB>(sr, si);
    ry_b<BA>(sr, si, cc[4], ss[4]);
    rz_b<BA>(sr, si, cc[5], ss[5]);
    ry_b<BB>(sr, si, cc[6], ss[6]);
}

// ============================ prep: weight transposes + ansatz-unitary fold ============================
__global__ void prep_kernel(const float* __restrict__ w1,   // (64,1,3,3)
                            const float* __restrict__ w2,   // (16,64,3,3)
                            const float* __restrict__ w3,   // (4,16,3,3)
                            const float* __restrict__ qp,   // (2,7)
                            const float* __restrict__ fc1w, // (64,196)
                            const float* __restrict__ fc2w, // (128,64)
                            const float* __restrict__ fc3w, // (64,128)
                            const float* __restrict__ fc4w, // (10,64)
                            unsigned short* __restrict__ w1b, // 2048 bf16
                            unsigned short* __restrict__ w2b, // 9216 bf16
                            float* __restrict__ w3t,         // 576
                            float* __restrict__ ab,          // 512
                            float* __restrict__ fc1t,        // (196,64)
                            float* __restrict__ fc2t,        // (64,128)
                            float* __restrict__ fc3t,        // (128,64)
                            float* __restrict__ fc4t)        // (64,10)
{
    int t = blockIdx.x * blockDim.x + threadIdx.x;
    int NT = gridDim.x * blockDim.x;
    for (int i = t; i < 2048; i += NT) {
        int j = i & 7, oc = (i >> 3) & 63, fqq = i >> 9;
        int tap = fqq * 8 + j;
        w1b[i] = tap < 9 ? f2bf(w1[oc * 9 + tap]) : (unsigned short)0;
    }
    for (int i = t; i < 9216; i += NT) {
        int j = i & 7, oc = (i >> 3) & 15, fq = (i >> 7) & 3, f = i >> 9;
        int tap = f >> 1, kk = f & 1;
        int s = kk * 32 + fq * 8 + j;            // K slot
        int ic = (s & 3) * 16 + (s >> 2);        // channel-slot permutation
        w2b[i] = f2bf(w2[(oc * 64 + ic) * 9 + tap]);
    }
    for (int i = t; i < 576; i += NT) {
        int c = i & 3, ch = (i >> 2) & 15, tap = i >> 6;
        w3t[i] = w3[(c * 16 + ch) * 9 + tap];
    }
    for (int i = t; i < 12544; i += NT) { int j = i / 196, k = i % 196; fc1t[k * 64 + j] = fc1w[i]; }
    for (int i = t; i < 8192;  i += NT) { int j = i / 64,  k = i % 64;  fc2t[k * 128 + j] = fc2w[i]; }
    for (int i = t; i < 8192;  i += NT) { int j = i / 128, k = i % 128; fc3t[k * 64 + j] = fc3w[i]; }
    for (int i = t; i < 640;   i += NT) { int j = i / 64,  k = i % 64;  fc4t[k * 10 + j] = fc4w[i]; }

    // fold the qp-only ansatz chain into U (16x16 complex); thread b = basis column b
    if (blockIdx.x == 0 && threadIdx.x < 16) {
        int b = threadIdx.x;
        float cs0[7], sn0[7], cs1[7], sn1[7];
        #pragma unroll
        for (int k = 0; k < 7; ++k) {
            __sincosf(qp[k] * 0.5f, &sn0[k], &cs0[k]);
            __sincosf(qp[7 + k] * 0.5f, &sn1[k], &cs1[k]);
        }
        float sr[16], si[16];
        #pragma unroll
        for (int i = 0; i < 16; ++i) { sr[i] = (i == b) ? 1.f : 0.f; si[i] = 0.f; }
        ansatz<0, 1>(sr, si, cs0, sn0);
        ansatz<1, 2>(sr, si, cs0, sn0);
        ansatz<2, 3>(sr, si, cs0, sn0);
        ansatz<3, 0>(sr, si, cs0, sn0);
        ansatz<0, 1>(sr, si, cs1, sn1);
        ansatz<1, 2>(sr, si, cs1, sn1);
        ansatz<2, 3>(sr, si, cs1, sn1);
        ansatz<3, 0>(sr, si, cs1, sn1);
        #pragma unroll
        for (int i = 0; i < 16; ++i) {
            ab[(i * 16 + b) * 2]     = sr[i];
            ab[(i * 16 + b) * 2 + 1] = si[i];
        }
    }
}

// ============================ fused conv1+pool+conv2+pool (both MFMA) ============================
// r13 structure (measured best): ring-zeroed pin/in_b/out2, 2 barriers total.
__global__ __launch_bounds__(256, 4) void conv12_kernel(
    const float* __restrict__ x,
    const float* __restrict__ b1, const unsigned short* __restrict__ w1b,
    const unsigned short* __restrict__ w2b,
    const float* __restrict__ b2, float* __restrict__ out2)
{
    __shared__ __align__(128) char lds_all[36864];
    float* pin = (float*)lds_all;                         // [30][34] f32, ring-zeroed
    char* in_b = lds_all + 4096;                          // 32 KB swizzled [256 grid][64 slots] bf16
    int t = threadIdx.x, lane = t & 63, wv = t >> 6;
    int fq = lane >> 4, fr = lane & 15;
    int n = blockIdx.x;

    // conv2 B fragments (L2-resident)
    bf16x8 bfrag[18];
    const bf16x8* wb = (const bf16x8*)w2b;
    #pragma unroll
    for (int f = 0; f < 18; ++f) bfrag[f] = wb[(f * 4 + fq) * 16 + fr];
    // conv1 B fragments + biases
    bf16x8 w1f[4];
    const bf16x8* wb1 = (const bf16x8*)w1b;
    float b1v[4];
    #pragma unroll
    for (int nt = 0; nt < 4; ++nt) {
        w1f[nt] = wb1[fq * 64 + nt * 16 + fr];
        b1v[nt] = b1[nt * 16 + fr];
    }
    float b2v = b2[fr];

    // zero the 60 pad cells of the swizzled tile (128 B each)
    for (int i = t; i < 480; i += 256) {
        int ci = i >> 3, sub = i & 7;
        int g;
        if (ci < 16)      g = ci;                  // row 0
        else if (ci < 32) g = 240 + (ci - 16);     // row 15
        else if (ci < 46) g = (ci - 31) * 16;      // col 0, rows 1..14
        else              g = (ci - 45) * 16 + 15; // col 15, rows 1..14
        *(f32x4*)(in_b + g * 128 + sub * 16) = f32x4{0.f, 0.f, 0.f, 0.f};
    }
    // zero ONLY pin's pad ring (rows 0/29, cols 0/29) — disjoint from staged interior
    if (t < 124) {
        int row, col;
        if (t < 68) { row = (t < 34) ? 0 : 29; col = (t < 34) ? t : t - 34; }
        else {
            int j = t - 68;
            if (j < 28) { row = j + 1;  col = 0; }
            else        { row = j - 27; col = 29; }
        }
        pin[row * 34 + col] = 0.f;
    }
    // zero out2's pad ring (32 cells x 16 ch = 128 float4) — global, no LDS dependency
    if (t >= 124 && t < 252) {
        int tt = t - 124;
        int cell = tt >> 2, comp = tt & 3;
        int pos;
        if (cell < 9)       pos = cell;                    // row 0
        else if (cell < 18) pos = 72 + (cell - 9);         // row 8
        else if (cell < 25) pos = (cell - 17) * 9;         // col 0, rows 1..7
        else                pos = (cell - 24) * 9 + 8;     // col 8, rows 1..7
        *reinterpret_cast<float4*>(out2 + (size_t)n * 1296 + pos * 16 + comp * 4)
            = float4{0.f, 0.f, 0.f, 0.f};
    }
    // stage image interior (disjoint from ring zeroing -> no barrier needed before)
    for (int i = t; i < 784; i += 256) pin[(i / 28 + 1) * 34 + (i % 28) + 1] = x[n * 784 + i];
    __syncthreads();

    // ---------------- phase 1: conv1 via MFMA + in-lane pool ----------------
    for (int tile = wv; tile < 49; tile += 4) {
        int pooledA = tile * 4 + (fr >> 2);
        int pyA = pooledA / 14, pxA = pooledA - pyA * 14;
        int Y = 2 * pyA + ((fr >> 1) & 1), X = 2 * pxA + (fr & 1);
        const float* ap = pin + Y * 34 + X + (fq == 1 ? 70 : 0);  // fq=1: j0 = tap8 @(+2,+2)
        float q0 = ap[0],  q1 = ap[1],  q2 = ap[2];
        float q3 = ap[34], q4 = ap[35], q5 = ap[36];
        float q6 = ap[68], q7 = ap[69];
        union { uint4 u; bf16x8 v; } A;
        A.u.x = pk2(q0, q1); A.u.y = pk2(q2, q3);
        A.u.z = pk2(q4, q5); A.u.w = pk2(q6, q7);

        f32x4 a0 = {0.f,0.f,0.f,0.f}, a1 = {0.f,0.f,0.f,0.f},
              a2 = {0.f,0.f,0.f,0.f}, a3 = {0.f,0.f,0.f,0.f};
        a0 = __builtin_amdgcn_mfma_f32_16x16x32_bf16(A.v, w1f[0], a0, 0, 0, 0);
        a1 = __builtin_amdgcn_mfma_f32_16x16x32_bf16(A.v, w1f[1], a1, 0, 0, 0);
        a2 = __builtin_amdgcn_mfma_f32_16x16x32_bf16(A.v, w1f[2], a2, 0, 0, 0);
        a3 = __builtin_amdgcn_mfma_f32_16x16x32_bf16(A.v, w1f[3], a3, 0, 0, 0);

        int pooled = tile * 4 + fq;          // 0..195
        int py = pooled / 14, px = pooled - py * 14;
        int grid = (py + 1) * 16 + (px + 1);
        unsigned swz = (unsigned)(grid & 7) << 4;
        float v0 = fmaxf(fmaxf(fmaxf(a0[0], a0[1]), fmaxf(a0[2], a0[3])) + b1v[0], 0.f);
        float v1 = fmaxf(fmaxf(fmaxf(a1[0], a1[1]), fmaxf(a1[2], a1[3])) + b1v[1], 0.f);
        float v2 = fmaxf(fmaxf(fmaxf(a2[0], a2[1]), fmaxf(a2[2], a2[3])) + b1v[2], 0.f);
        float v3 = fmaxf(fmaxf(fmaxf(a3[0], a3[1]), fmaxf(a3[2], a3[3])) + b1v[3], 0.f);
        uint2 w; w.x = pk2(v0, v1); w.y = pk2(v2, v3);    // slots fr*4 .. fr*4+3
        *reinterpret_cast<uint2*>(in_b + (((unsigned)grid * 128 + (unsigned)fr * 8) ^ swz)) = w;
    }
    __syncthreads();

    // ---------------- phase 2: conv2 via MFMA, in-lane pool, direct store ----------------
    for (int tile = wv; tile < 13; tile += 4) {
        f32x4 acc = {0.f, 0.f, 0.f, 0.f};
        int pv = tile * 4 + (fr >> 2); pv = pv > 48 ? 48 : pv;   // clamp tail rows
        int sub = fr & 3;
        int y7 = pv / 7, x7 = pv - y7 * 7;
        int y = 2 * y7 + (sub >> 1), xx = 2 * x7 + (sub & 1);    // pre-pool pos 0..13
        int g0 = y * 16 + xx;
        int vb = g0 * 128 + fq * 16;
        #pragma unroll
        for (int ky = 0; ky < 3; ++ky)
            #pragma unroll
            for (int kx = 0; kx < 3; ++kx) {
                int dg = ky * 16 + kx;
                int msk = ((g0 + dg) & 7) << 4;
                int lin = vb + dg * 128;
                bf16x8 a0 = *(const bf16x8*)(in_b + (lin ^ msk));
                acc = __builtin_amdgcn_mfma_f32_16x16x32_bf16(a0, bfrag[(ky * 3 + kx) * 2], acc, 0, 0, 0);
                bf16x8 a1 = *(const bf16x8*)(in_b + ((lin | 64) ^ msk));
                acc = __builtin_amdgcn_mfma_f32_16x16x32_bf16(a1, bfrag[(ky * 3 + kx) * 2 + 1], acc, 0, 0, 0);
            }
        int pooled2 = tile * 4 + fq;                 // 0..51
        if (pooled2 < 49) {
            float m = fmaxf(fmaxf(acc[0], acc[1]), fmaxf(acc[2], acc[3]));
            int y9 = pooled2 / 7, x9 = pooled2 - y9 * 7;
            out2[(size_t)n * 1296 + ((y9 + 1) * 9 + (x9 + 1)) * 16 + fr] =
                fmaxf(m + b2v, 0.f);
        }
    }
}

// ============================ fused conv3+quantum+MLP (8 images/block) ============================
// out2 padded NHWC (2048, 9x9, 16), ab = U(16x16 complex) -> out:(2048,10)
__global__ __launch_bounds__(512) void qfc_kernel(
    const float* __restrict__ out2, const float* __restrict__ w3t,
    const float* __restrict__ b3, const float* __restrict__ ab,
    const float* __restrict__ fc1t, const float* __restrict__ fb1,
    const float* __restrict__ fc2t, const float* __restrict__ fb2,
    const float* __restrict__ fc3t, const float* __restrict__ fb3,
    const float* __restrict__ fc4t, const float* __restrict__ fb4,
    float* __restrict__ out)
{
    __shared__ float qr[8][196];
    __shared__ float h1[8][64], h2[8][128], h3[8][64];
    int t = threadIdx.x;
    int nb = blockIdx.x * 8;              // 256 blocks x 8 = 2048

    // ---- patch phase: threads 0..391, one (image, patch) each ----
    if (t < 392) {
        int nl = t / 49, p = t - nl * 49;
        int n = nb + nl;
        int py = p / 7, px = p - py * 7;
        const float* in = out2 + (size_t)n * 1296;

        float acc0 = b3[0], acc1 = b3[1], acc2 = b3[2], acc3 = b3[3];
        #pragma unroll
        for (int ky = 0; ky < 3; ++ky)
            #pragma unroll
            for (int kx = 0; kx < 3; ++kx) {
                const float* cp = in + ((py + ky) * 9 + (px + kx)) * 16;   // pad ring is zero
                const float* wt = w3t + (ky * 3 + kx) * 64;                // uniform -> s_load
                #pragma unroll
                for (int icq = 0; icq < 4; ++icq) {
                    float4 v4 = *reinterpret_cast<const float4*>(cp + icq * 4);
                    const float* wq = wt + icq * 16;
                    acc0 = fmaf(wq[0],  v4.x, acc0); acc1 = fmaf(wq[1],  v4.x, acc1);
                    acc2 = fmaf(wq[2],  v4.x, acc2); acc3 = fmaf(wq[3],  v4.x, acc3);
                    acc0 = fmaf(wq[4],  v4.y, acc0); acc1 = fmaf(wq[5],  v4.y, acc1);
                    acc2 = fmaf(wq[6],  v4.y, acc2); acc3 = fmaf(wq[7],  v4.y, acc3);
                    acc0 = fmaf(wq[8],  v4.z, acc0); acc1 = fmaf(wq[9],  v4.z, acc1);
                    acc2 = fmaf(wq[10], v4.z, acc2); acc3 = fmaf(wq[11], v4.z, acc3);
                    acc0 = fmaf(wq[12], v4.w, acc0); acc1 = fmaf(wq[13], v4.w, acc1);
                    acc2 = fmaf(wq[14], v4.w, acc2); acc3 = fmaf(wq[15], v4.w, acc3);
                }
            }

        float cw[4], sw[4];
        {
            float az[4] = {acc0, acc1, acc2, acc3};
            #pragma unroll
            for (int c = 0; c < 4; ++c) {
                float z = az[c];
                z = z > 0.f ? z : 0.01f * z;
                float sg = 1.f / (1.f + __expf(-z));
                __sincosf(1.5707963267948966f * sg, &sw[c], &cw[c]);
            }
        }
        float p01[4] = { cw[0]*cw[1], cw[0]*sw[1], sw[0]*cw[1], sw[0]*sw[1] };
        float p23[4] = { cw[2]*cw[3], cw[2]*sw[3], sw[2]*cw[3], sw[2]*sw[3] };
        float v[16];
        #pragma unroll
        for (int i = 0; i < 16; ++i) v[i] = p01[i >> 2] * p23[i & 3];

        float e0 = 0.f, e1 = 0.f, e2 = 0.f, e3 = 0.f;
        #pragma unroll
        for (int i = 0; i < 16; ++i) {
            const float* row = ab + i * 32;          // uniform -> s_load
            float re = 0.f, im = 0.f;
            #pragma unroll
            for (int k = 0; k < 16; ++k) {
                re = fmaf(row[k * 2],     v[k], re);
                im = fmaf(row[k * 2 + 1], v[k], im);
            }
            float p2 = re * re + im * im;
            e0 += (i & 8) ? -p2 : p2;
            e1 += (i & 4) ? -p2 : p2;
            e2 += (i & 2) ? -p2 : p2;
            e3 += (i & 1) ? -p2 : p2;
        }
        *reinterpret_cast<float4*>(&qr[nl][p * 4]) = float4{e0, e1, e2, e3};
    }
    __syncthreads();

    // ---- fc phase: wave = image ----
    int wv = t >> 6, lane = t & 63;
    int n = nb + wv;
    float a = fb1[lane];
    for (int k = 0; k < 196; ++k) a = fmaf(fc1t[k * 64 + lane], qr[wv][k], a);
    h1[wv][lane] = fmaxf(a, 0.f);
    __syncthreads();
    float a0 = fb2[lane], a1 = fb2[lane + 64];
    for (int k = 0; k < 64; ++k) {
        float vv = h1[wv][k];
        a0 = fmaf(fc2t[k * 128 + lane], vv, a0);
        a1 = fmaf(fc2t[k * 128 + lane + 64], vv, a1);
    }
    h2[wv][lane] = a0; h2[wv][lane + 64] = a1;
    __syncthreads();
    a = fb3[lane];
    for (int k = 0; k < 128; ++k) a = fmaf(fc3t[k * 64 + lane], h2[wv][k], a);
    h3[wv][lane] = fmaxf(a, 0.f);
    __syncthreads();
    if (lane < 10) {
        a = fb4[lane];
        for (int k = 0; k < 64; ++k) a = fmaf(fc4t[k * 10 + lane], h3[wv][k], a);
        out[(size_t)n * 10 + lane] = a;
    }
}

// ============================ launch ============================
extern "C" void kernel_launch(void* const* d_in, const int* in_sizes, int n_in,
                              void* d_out, int out_size, void* d_ws, size_t ws_size,
                              hipStream_t stream) {
    const float* x      = (const float*)d_in[0];
    const float* c1w    = (const float*)d_in[1];
    const float* c1b    = (const float*)d_in[2];
    const float* c2w    = (const float*)d_in[3];
    const float* c2b    = (const float*)d_in[4];
    const float* c3w    = (const float*)d_in[5];
    const float* c3b    = (const float*)d_in[6];
    const float* qp     = (const float*)d_in[7];
    const float* fc1w   = (const float*)d_in[8];
    const float* fc1b   = (const float*)d_in[9];
    const float* fc2w   = (const float*)d_in[10];
    const float* fc2b   = (const float*)d_in[11];
    const float* fc3w   = (const float*)d_in[12];
    const float* fc3b   = (const float*)d_in[13];
    const float* fc4w   = (const float*)d_in[14];
    const float* fc4b   = (const float*)d_in[15];
    float* out = (float*)d_out;

    float* ws = (float*)d_ws;
    unsigned short* w2b = (unsigned short*)ws;            // 9216 bf16 (4608 float slots)
    unsigned short* w1b = (unsigned short*)(ws + 4608);   // 2048 bf16 (1024 float slots)
    float* w3t  = ws + 5632;                              // 576
    float* abm  = ws + 6208;                              // 512
    float* fc1t = ws + 6720;                              // 12544
    float* fc2t = fc1t + 12544;                           // 8192
    float* fc3t = fc2t + 8192;                            // 8192
    float* fc4t = fc3t + 8192;                            // 640
    float* out2 = fc4t + 640;                             // 2048*1296 f32 (padded 9x9x16)

    prep_kernel<<<40, 256, 0, stream>>>(c1w, c2w, c3w, qp, fc1w, fc2w, fc3w, fc4w,
                                        w1b, w2b, w3t, abm, fc1t, fc2t, fc3t, fc4t);
    conv12_kernel<<<2048, 256, 0, stream>>>(x, c1b, w1b, w2b, c2b, out2);
    qfc_kernel<<<256, 512, 0, stream>>>(out2, w3t, c3b, abm,
                                        fc1t, fc1b, fc2t, fc2b,
                                        fc3t, fc3b, fc4t, fc4b, out);
}